// Round 2
// baseline (177.465 us; speedup 1.0000x reference)
//
#include <hip/hip_runtime.h>
#include <hip/hip_bf16.h>

// Encoder: neigh_feats = mean(raw[idx], axis=1); x = nf @ W; BN(train); LeakyReLU(0.01)
// Inputs: raw[100000,128]f32, W[128,128]f32, gamma[128], beta[128], idx[50000,16]i32
// Output: [50000,128] f32
//
// R2: B-fragments of W live in VGPRs (loaded once per block from global, bf16) —
// frees ~35KB LDS -> occupancy VGPR-bound; gather loads batched 8-deep for MLP.
// enc_bn hoists scale/shift to registers (e&31 is thread-invariant).

#define NTOTAL 100000
#define FEAT   128
#define NB     50000
#define KNEI   16
#define NTILES (NB / 16)   // 3125 exact
#define GRID_A 1563        // ~2 tiles/block, balanced; keeps per-address atomics ~1.5k

typedef float f32x4 __attribute__((ext_vector_type(4)));
typedef short bf16x8 __attribute__((ext_vector_type(8)));

__device__ __forceinline__ unsigned short f2bf(float f) {
    union { float f; unsigned u; } v; v.f = f;
    unsigned r = v.u + 0x7FFF + ((v.u >> 16) & 1);   // round-to-nearest-even
    return (unsigned short)(r >> 16);
}

#define A_LD  136   // bf16 elems; pad 8 keeps 16B align, 2-way banks only (free)

__global__ __launch_bounds__(256, 4) void enc_gemm(
    const float* __restrict__ raw, const float* __restrict__ W,
    const int* __restrict__ idx, float* __restrict__ out,
    float* __restrict__ gstats)
{
    __shared__ unsigned short sA[16 * A_LD];     // 4352 B
    __shared__ int sidx[256];                    // 1024 B

    const int t = threadIdx.x;
    const int lane = t & 63;
    const int wv = t >> 6;        // wave 0..3 -> n-chunk of 32
    const int ln = lane & 15;
    const int qd = lane >> 4;     // quad 0..3
    const int c = t & 31;         // float4 chunk within a 128-f row
    const int g = t >> 5;         // row-pair group 0..7

    // B-fragments in registers: wave wv covers n0=wv*32+ln and n1=n0+16.
    // Per kt: lane needs W[k0+j][n] for j=0..7, k0=kt*32+qd*8.
    const int n0 = wv * 32 + ln, n1 = n0 + 16;
    bf16x8 bf0[4], bf1[4];
    #pragma unroll
    for (int kt = 0; kt < 4; ++kt) {
        const int k0 = kt * 32 + qd * 8;
        #pragma unroll
        for (int j = 0; j < 8; ++j) {
            bf0[kt][j] = (short)f2bf(W[(k0 + j) * FEAT + n0]);
            bf1[kt][j] = (short)f2bf(W[(k0 + j) * FEAT + n1]);
        }
    }

    float s1a = 0.f, s2a = 0.f, s1b = 0.f, s2b = 0.f;
    const float4* raw4 = (const float4*)raw;

    for (int tile = blockIdx.x; tile < NTILES; tile += gridDim.x) {
        const int i0 = tile * 16;
        __syncthreads();                       // protect sidx/sA reuse from prior iter
        sidx[t] = idx[i0 * KNEI + t];          // 256 ints, coalesced
        __syncthreads();

        // Gather + mean: thread handles rows g*2, g*2+1, float4-chunk c.
        // Per-instruction: one wave reads 2 full 512B rows (perfectly coalesced).
        // 8-deep load batches maximize outstanding vmem.
        #pragma unroll
        for (int rr = 0; rr < 2; ++rr) {
            const int r = g * 2 + rr;
            const int* ip = &sidx[r * KNEI];
            float4 v[8];
            float ax = 0.f, ay = 0.f, az = 0.f, aw = 0.f;
            float bx = 0.f, by = 0.f, bz = 0.f, bw = 0.f;
            #pragma unroll
            for (int k = 0; k < 8; ++k) v[k] = raw4[(size_t)ip[k] * 32 + c];
            #pragma unroll
            for (int k = 0; k < 8; k += 2) {
                ax += v[k].x;   ay += v[k].y;   az += v[k].z;   aw += v[k].w;
                bx += v[k+1].x; by += v[k+1].y; bz += v[k+1].z; bw += v[k+1].w;
            }
            #pragma unroll
            for (int k = 0; k < 8; ++k) v[k] = raw4[(size_t)ip[k + 8] * 32 + c];
            #pragma unroll
            for (int k = 0; k < 8; k += 2) {
                ax += v[k].x;   ay += v[k].y;   az += v[k].z;   aw += v[k].w;
                bx += v[k+1].x; by += v[k+1].y; bz += v[k+1].z; bw += v[k+1].w;
            }
            ushort4 b;
            b.x = f2bf((ax + bx) * 0.0625f); b.y = f2bf((ay + by) * 0.0625f);
            b.z = f2bf((az + bz) * 0.0625f); b.w = f2bf((aw + bw) * 0.0625f);
            *(ushort4*)&sA[r * A_LD + c * 4] = b;   // 8B store, 8B aligned
        }
        __syncthreads();

        // MFMA: wave wv computes n-tiles n0 and n1 for all 16 rows.
        f32x4 acc0 = {0.f, 0.f, 0.f, 0.f}, acc1 = {0.f, 0.f, 0.f, 0.f};
        #pragma unroll
        for (int kt = 0; kt < 4; ++kt) {
            const int k0 = kt * 32 + qd * 8;
            bf16x8 a = *(const bf16x8*)&sA[ln * A_LD + k0];
            acc0 = __builtin_amdgcn_mfma_f32_16x16x32_bf16(a, bf0[kt], acc0, 0, 0, 0);
            acc1 = __builtin_amdgcn_mfma_f32_16x16x32_bf16(a, bf1[kt], acc1, 0, 0, 0);
        }

        // Epilogue: C/D layout col=lane&15, row=qd*4+reg. Write x, accumulate stats.
        #pragma unroll
        for (int ri = 0; ri < 4; ++ri) {
            const int row = i0 + qd * 4 + ri;
            float v0 = acc0[ri], v1 = acc1[ri];
            out[row * FEAT + n0] = v0;
            out[row * FEAT + n1] = v1;
            s1a += v0; s2a += v0 * v0;
            s1b += v1; s2b += v1 * v1;
        }
    }

    // Reduce quads within wave (lanes l, l+16, l+32, l+48 share feature n)
    s1a += __shfl_down(s1a, 32); s1a += __shfl_down(s1a, 16);
    s2a += __shfl_down(s2a, 32); s2a += __shfl_down(s2a, 16);
    s1b += __shfl_down(s1b, 32); s1b += __shfl_down(s1b, 16);
    s2b += __shfl_down(s2b, 32); s2b += __shfl_down(s2b, 16);
    if (qd == 0) {
        atomicAdd(&gstats[n0], s1a);
        atomicAdd(&gstats[FEAT + n0], s2a);
        atomicAdd(&gstats[n1], s1b);
        atomicAdd(&gstats[FEAT + n1], s2b);
    }
}

__global__ __launch_bounds__(256) void enc_bn(
    float* __restrict__ out, const float* __restrict__ gstats,
    const float* __restrict__ gamma, const float* __restrict__ beta)
{
    __shared__ float sScale[FEAT], sShift[FEAT];
    const int t = threadIdx.x;
    if (t < FEAT) {
        float s1 = gstats[t], s2 = gstats[FEAT + t];
        float mean = s1 * (1.0f / NB);
        float var = s2 * (1.0f / NB) - mean * mean;
        float sc = gamma[t] * rsqrtf(var + 1e-5f);
        sScale[t] = sc;
        sShift[t] = beta[t] - mean * sc;
    }
    __syncthreads();

    // e & 31 is invariant per thread (blockDim=256, strides are multiples of 32)
    const int f4 = (t & 31) * 4;
    const float4 sc = *(const float4*)&sScale[f4];
    const float4 sh = *(const float4*)&sShift[f4];

    const int total4 = NB * FEAT / 4;   // 1.6M float4
    float4* o4 = (float4*)out;
    for (int e = blockIdx.x * blockDim.x + t; e < total4; e += gridDim.x * blockDim.x) {
        float4 v = o4[e];
        float4 r;
        float y;
        y = v.x * sc.x + sh.x; r.x = (y >= 0.f) ? y : 0.01f * y;
        y = v.y * sc.y + sh.y; r.y = (y >= 0.f) ? y : 0.01f * y;
        y = v.z * sc.z + sh.z; r.z = (y >= 0.f) ? y : 0.01f * y;
        y = v.w * sc.w + sh.w; r.w = (y >= 0.f) ? y : 0.01f * y;
        o4[e] = r;
    }
}

extern "C" void kernel_launch(void* const* d_in, const int* in_sizes, int n_in,
                              void* d_out, int out_size, void* d_ws, size_t ws_size,
                              hipStream_t stream) {
    const float* raw   = (const float*)d_in[0];
    const float* W     = (const float*)d_in[1];
    const float* gamma = (const float*)d_in[2];
    const float* beta  = (const float*)d_in[3];
    const int*   idx   = (const int*)d_in[4];
    float* out = (float*)d_out;
    float* gstats = (float*)d_ws;   // [0:128] sum, [128:256] sumsq

    hipMemsetAsync(gstats, 0, 2 * FEAT * sizeof(float), stream);
    enc_gemm<<<GRID_A, 256, 0, stream>>>(raw, W, idx, out, gstats);
    enc_bn<<<1024, 256, 0, stream>>>(out, gstats, gamma, beta);
}

// Round 3
// 151.922 us; speedup vs baseline: 1.1681x; 1.1681x over previous
//
#include <hip/hip_runtime.h>
#include <hip/hip_bf16.h>

// Encoder: neigh_feats = mean(raw[idx], axis=1); x = nf @ W; BN(train); LeakyReLU(0.01)
// Inputs: raw[100000,128]f32, W[128,128]f32, gamma[128], beta[128], idx[50000,16]i32
// Output: [50000,128] f32
//
// R3: gather traffic is the bottleneck (L2-miss line requests on random 512B rows).
// Pre-convert raw to bf16 rows (256B) in d_ws -> halves gather bytes AND line count.
// Also: W pre-transposed to bf16 in ws (coalesced LDS staging, no per-block f2bf),
// x written as bf16 to ws (halves BN input), gstats zeroed in conv (no memset dispatch).
// Fallback to the R1 f32 path if ws_size is too small.

#define NTOTAL 100000
#define FEAT   128
#define NB     50000
#define KNEI   16
#define NTILES (NB / 16)   // 3125 exact

// d_ws layout (bf16 path)
#define OFF_STATS 0                         // 256 f32 = 1 KB
#define OFF_WT    1024                      // 128*128 bf16 = 32 KB
#define OFF_RAWB  33792                     // 100000*128 bf16 = 25.6 MB
#define OFF_XB    (33792 + 25600000)        // 50000*128 bf16 = 12.8 MB
#define WS_NEEDED (OFF_XB + 12800000)

typedef float f32x4 __attribute__((ext_vector_type(4)));
typedef short bf16x8 __attribute__((ext_vector_type(8)));

__device__ __forceinline__ unsigned short f2bf(float f) {
    union { float f; unsigned u; } v; v.f = f;
    unsigned r = v.u + 0x7FFF + ((v.u >> 16) & 1);   // round-to-nearest-even
    return (unsigned short)(r >> 16);
}

#define WT_LD 136   // bf16 elems; pad 8: 16B-aligned rows, 2-way banks only (free)
#define A_LD  136

// ---------------- conv: raw f32 -> bf16, W -> Wt bf16 transposed, zero stats ----
__global__ __launch_bounds__(256) void enc_conv(
    const float* __restrict__ raw, const float* __restrict__ W,
    unsigned short* __restrict__ rawb, unsigned short* __restrict__ Wt,
    float* __restrict__ gstats)
{
    const int t = threadIdx.x;
    if (blockIdx.x < 64) {               // Wt[n*128+k] = bf16(W[k*128+n]), coalesced writes
        int e = blockIdx.x * 256 + t;    // 0..16383
        int n = e >> 7, k = e & 127;
        Wt[e] = f2bf(W[k * FEAT + n]);
    }
    if (blockIdx.x == 64 && t < 2 * FEAT) gstats[t] = 0.f;

    const float4* raw4 = (const float4*)raw;
    ushort4* rb4 = (ushort4*)rawb;
    const int NQ = NTOTAL * FEAT / 4;    // 3.2M
    for (int e = blockIdx.x * 256 + t; e < NQ; e += gridDim.x * 256) {
        float4 v = raw4[e];
        ushort4 b;
        b.x = f2bf(v.x); b.y = f2bf(v.y); b.z = f2bf(v.z); b.w = f2bf(v.w);
        rb4[e] = b;
    }
}

// ---------------- gemm (bf16 path): gather bf16 rows, MFMA, x->bf16, stats -------
__global__ __launch_bounds__(256, 4) void enc_gemm_b(
    const unsigned short* __restrict__ rawb, const unsigned short* __restrict__ Wt,
    const int* __restrict__ idx, unsigned short* __restrict__ xb,
    float* __restrict__ gstats)
{
    __shared__ unsigned short sWt[128 * WT_LD];  // 34816 B
    __shared__ unsigned short sA[16 * A_LD];     //  4352 B
    __shared__ int sidx[256];                    //  1024 B

    const int t = threadIdx.x;

    // Stage Wt (already bf16, n-major) into padded LDS: 2048 16B chunks, coalesced.
    #pragma unroll
    for (int i = 0; i < 8; ++i) {
        int e = t + i * 256;
        int n = e >> 4, c = e & 15;
        *(uint4*)&sWt[n * WT_LD + c * 8] = *(const uint4*)&Wt[n * 128 + c * 8];
    }

    const int lane = t & 63;
    const int wv = t >> 6;        // wave 0..3 -> n-chunk of 32
    const int ln = lane & 15;
    const int qd = lane >> 4;     // quad 0..3
    const int c2 = t & 15;        // 16B chunk within 256B bf16 row
    const int g  = t >> 4;        // output row 0..15
    const int n0 = wv * 32 + ln, n1 = n0 + 16;

    float s1a = 0.f, s2a = 0.f, s1b = 0.f, s2b = 0.f;

    for (int tile = blockIdx.x; tile < NTILES; tile += gridDim.x) {
        const int i0 = tile * 16;
        __syncthreads();                       // protect sidx/sA reuse (fences sWt on iter 0)
        sidx[t] = idx[i0 * KNEI + t];          // 256 ints, coalesced
        __syncthreads();

        // Gather + mean: thread owns output row g, 16B chunk c2; all 16 neighbor
        // loads issued back-to-back (16 outstanding 16B vmem / thread).
        // Per wave-instr: 4 random 256B rows, perfectly coalesced.
        {
            const int* ip = &sidx[g * KNEI];
            uint4 v[16];
            #pragma unroll
            for (int k = 0; k < KNEI; ++k)
                v[k] = *(const uint4*)&rawb[(size_t)ip[k] * FEAT + c2 * 8];
            float a0=0.f,a1=0.f,a2=0.f,a3=0.f,a4=0.f,a5=0.f,a6=0.f,a7=0.f;
            #pragma unroll
            for (int k = 0; k < KNEI; ++k) {
                a0 += __uint_as_float(v[k].x << 16);
                a1 += __uint_as_float(v[k].x & 0xFFFF0000u);
                a2 += __uint_as_float(v[k].y << 16);
                a3 += __uint_as_float(v[k].y & 0xFFFF0000u);
                a4 += __uint_as_float(v[k].z << 16);
                a5 += __uint_as_float(v[k].z & 0xFFFF0000u);
                a6 += __uint_as_float(v[k].w << 16);
                a7 += __uint_as_float(v[k].w & 0xFFFF0000u);
            }
            uint4 b;
            b.x = (unsigned)f2bf(a0 * 0.0625f) | ((unsigned)f2bf(a1 * 0.0625f) << 16);
            b.y = (unsigned)f2bf(a2 * 0.0625f) | ((unsigned)f2bf(a3 * 0.0625f) << 16);
            b.z = (unsigned)f2bf(a4 * 0.0625f) | ((unsigned)f2bf(a5 * 0.0625f) << 16);
            b.w = (unsigned)f2bf(a6 * 0.0625f) | ((unsigned)f2bf(a7 * 0.0625f) << 16);
            *(uint4*)&sA[g * A_LD + c2 * 8] = b;
        }
        __syncthreads();

        // MFMA: wave wv computes n-tiles n0, n1 for all 16 rows.
        f32x4 acc0 = {0.f, 0.f, 0.f, 0.f}, acc1 = {0.f, 0.f, 0.f, 0.f};
        #pragma unroll
        for (int kt = 0; kt < 4; ++kt) {
            const int k0 = kt * 32 + qd * 8;
            bf16x8 a  = *(const bf16x8*)&sA[ln * A_LD + k0];
            bf16x8 b0 = *(const bf16x8*)&sWt[n0 * WT_LD + k0];
            bf16x8 b1 = *(const bf16x8*)&sWt[n1 * WT_LD + k0];
            acc0 = __builtin_amdgcn_mfma_f32_16x16x32_bf16(a, b0, acc0, 0, 0, 0);
            acc1 = __builtin_amdgcn_mfma_f32_16x16x32_bf16(a, b1, acc1, 0, 0, 0);
        }

        // Epilogue: C/D layout col=lane&15, row=qd*4+reg. x -> bf16 ws; stats in f32.
        #pragma unroll
        for (int ri = 0; ri < 4; ++ri) {
            const int row = i0 + qd * 4 + ri;
            float v0 = acc0[ri], v1 = acc1[ri];
            xb[row * FEAT + n0] = f2bf(v0);
            xb[row * FEAT + n1] = f2bf(v1);
            s1a += v0; s2a += v0 * v0;
            s1b += v1; s2b += v1 * v1;
        }
    }

    s1a += __shfl_down(s1a, 32); s1a += __shfl_down(s1a, 16);
    s2a += __shfl_down(s2a, 32); s2a += __shfl_down(s2a, 16);
    s1b += __shfl_down(s1b, 32); s1b += __shfl_down(s1b, 16);
    s2b += __shfl_down(s2b, 32); s2b += __shfl_down(s2b, 16);
    if (qd == 0) {
        atomicAdd(&gstats[n0], s1a);
        atomicAdd(&gstats[FEAT + n0], s2a);
        atomicAdd(&gstats[n1], s1b);
        atomicAdd(&gstats[FEAT + n1], s2b);
    }
}

// ---------------- bn (bf16 path): xb -> normalized f32 out ----------------------
__global__ __launch_bounds__(256) void enc_bn_b(
    const unsigned short* __restrict__ xb, float* __restrict__ out,
    const float* __restrict__ gstats,
    const float* __restrict__ gamma, const float* __restrict__ beta)
{
    __shared__ float sScale[FEAT], sShift[FEAT];
    const int t = threadIdx.x;
    if (t < FEAT) {
        float s1 = gstats[t], s2 = gstats[FEAT + t];
        float mean = s1 * (1.0f / NB);
        float var = s2 * (1.0f / NB) - mean * mean;
        float sc = gamma[t] * rsqrtf(var + 1e-5f);
        sScale[t] = sc;
        sShift[t] = beta[t] - mean * sc;
    }
    __syncthreads();

    const int f8 = (t & 15) * 8;               // thread-invariant feature octet
    const float4 sc0 = *(const float4*)&sScale[f8], sc1 = *(const float4*)&sScale[f8 + 4];
    const float4 sh0 = *(const float4*)&sShift[f8], sh1 = *(const float4*)&sShift[f8 + 4];

    const uint4* x4 = (const uint4*)xb;
    float4* o4 = (float4*)out;
    const int total8 = NB * FEAT / 8;          // 800k
    for (int e = blockIdx.x * 256 + t; e < total8; e += gridDim.x * 256) {
        uint4 v = x4[e];
        float4 r0, r1; float y;
        y = __uint_as_float(v.x << 16)        * sc0.x + sh0.x; r0.x = (y >= 0.f) ? y : 0.01f * y;
        y = __uint_as_float(v.x & 0xFFFF0000u)* sc0.y + sh0.y; r0.y = (y >= 0.f) ? y : 0.01f * y;
        y = __uint_as_float(v.y << 16)        * sc0.z + sh0.z; r0.z = (y >= 0.f) ? y : 0.01f * y;
        y = __uint_as_float(v.y & 0xFFFF0000u)* sc0.w + sh0.w; r0.w = (y >= 0.f) ? y : 0.01f * y;
        y = __uint_as_float(v.z << 16)        * sc1.x + sh1.x; r1.x = (y >= 0.f) ? y : 0.01f * y;
        y = __uint_as_float(v.z & 0xFFFF0000u)* sc1.y + sh1.y; r1.y = (y >= 0.f) ? y : 0.01f * y;
        y = __uint_as_float(v.w << 16)        * sc1.z + sh1.z; r1.z = (y >= 0.f) ? y : 0.01f * y;
        y = __uint_as_float(v.w & 0xFFFF0000u)* sc1.w + sh1.w; r1.w = (y >= 0.f) ? y : 0.01f * y;
        o4[e * 2] = r0; o4[e * 2 + 1] = r1;
    }
}

// ======================= fallback (R1, f32 path) ===============================
__global__ __launch_bounds__(256, 4) void enc_gemm_f(
    const float* __restrict__ raw, const float* __restrict__ W,
    const int* __restrict__ idx, float* __restrict__ out,
    float* __restrict__ gstats)
{
    __shared__ unsigned short sWt[128 * WT_LD];
    __shared__ unsigned short sA[16 * A_LD];
    __shared__ int sidx[256];
    const int t = threadIdx.x;
    #pragma unroll 4
    for (int i = 0; i < 64; ++i) {
        int e = t + i * 256;
        int f = e >> 7, n = e & 127;
        sWt[n * WT_LD + f] = f2bf(W[e]);
    }
    const int lane = t & 63, wv = t >> 6, ln = lane & 15, qd = lane >> 4;
    const int c = t & 31, g = t >> 5;
    const int n0 = wv * 32 + ln, n1 = n0 + 16;
    float s1a = 0.f, s2a = 0.f, s1b = 0.f, s2b = 0.f;
    const float4* raw4 = (const float4*)raw;
    for (int tile = blockIdx.x; tile < NTILES; tile += gridDim.x) {
        const int i0 = tile * 16;
        __syncthreads();
        sidx[t] = idx[i0 * KNEI + t];
        __syncthreads();
        #pragma unroll
        for (int rr = 0; rr < 2; ++rr) {
            const int r = g * 2 + rr;
            const int* ip = &sidx[r * KNEI];
            float4 acc = {0.f, 0.f, 0.f, 0.f};
            #pragma unroll
            for (int k = 0; k < KNEI; ++k) {
                float4 v = raw4[(size_t)ip[k] * 32 + c];
                acc.x += v.x; acc.y += v.y; acc.z += v.z; acc.w += v.w;
            }
            ushort4 b;
            b.x = f2bf(acc.x * 0.0625f); b.y = f2bf(acc.y * 0.0625f);
            b.z = f2bf(acc.z * 0.0625f); b.w = f2bf(acc.w * 0.0625f);
            *(ushort4*)&sA[r * A_LD + c * 4] = b;
        }
        __syncthreads();
        f32x4 acc0 = {0.f, 0.f, 0.f, 0.f}, acc1 = {0.f, 0.f, 0.f, 0.f};
        #pragma unroll
        for (int kt = 0; kt < 4; ++kt) {
            const int k0 = kt * 32 + qd * 8;
            bf16x8 a  = *(const bf16x8*)&sA[ln * A_LD + k0];
            bf16x8 b0 = *(const bf16x8*)&sWt[n0 * WT_LD + k0];
            bf16x8 b1 = *(const bf16x8*)&sWt[n1 * WT_LD + k0];
            acc0 = __builtin_amdgcn_mfma_f32_16x16x32_bf16(a, b0, acc0, 0, 0, 0);
            acc1 = __builtin_amdgcn_mfma_f32_16x16x32_bf16(a, b1, acc1, 0, 0, 0);
        }
        #pragma unroll
        for (int ri = 0; ri < 4; ++ri) {
            const int row = i0 + qd * 4 + ri;
            float v0 = acc0[ri], v1 = acc1[ri];
            out[row * FEAT + n0] = v0;
            out[row * FEAT + n1] = v1;
            s1a += v0; s2a += v0 * v0;
            s1b += v1; s2b += v1 * v1;
        }
    }
    s1a += __shfl_down(s1a, 32); s1a += __shfl_down(s1a, 16);
    s2a += __shfl_down(s2a, 32); s2a += __shfl_down(s2a, 16);
    s1b += __shfl_down(s1b, 32); s1b += __shfl_down(s1b, 16);
    s2b += __shfl_down(s2b, 32); s2b += __shfl_down(s2b, 16);
    if (qd == 0) {
        atomicAdd(&gstats[n0], s1a);
        atomicAdd(&gstats[FEAT + n0], s2a);
        atomicAdd(&gstats[n1], s1b);
        atomicAdd(&gstats[FEAT + n1], s2b);
    }
}

__global__ __launch_bounds__(256) void enc_bn_f(
    float* __restrict__ out, const float* __restrict__ gstats,
    const float* __restrict__ gamma, const float* __restrict__ beta)
{
    __shared__ float sScale[FEAT], sShift[FEAT];
    const int t = threadIdx.x;
    if (t < FEAT) {
        float s1 = gstats[t], s2 = gstats[FEAT + t];
        float mean = s1 * (1.0f / NB);
        float var = s2 * (1.0f / NB) - mean * mean;
        float sc = gamma[t] * rsqrtf(var + 1e-5f);
        sScale[t] = sc;
        sShift[t] = beta[t] - mean * sc;
    }
    __syncthreads();
    const int f4 = (t & 31) * 4;
    const float4 sc = *(const float4*)&sScale[f4];
    const float4 sh = *(const float4*)&sShift[f4];
    const int total4 = NB * FEAT / 4;
    float4* o4 = (float4*)out;
    for (int e = blockIdx.x * 256 + t; e < total4; e += gridDim.x * 256) {
        float4 v = o4[e];
        float4 r; float y;
        y = v.x * sc.x + sh.x; r.x = (y >= 0.f) ? y : 0.01f * y;
        y = v.y * sc.y + sh.y; r.y = (y >= 0.f) ? y : 0.01f * y;
        y = v.z * sc.z + sh.z; r.z = (y >= 0.f) ? y : 0.01f * y;
        y = v.w * sc.w + sh.w; r.w = (y >= 0.f) ? y : 0.01f * y;
        o4[e] = r;
    }
}

extern "C" void kernel_launch(void* const* d_in, const int* in_sizes, int n_in,
                              void* d_out, int out_size, void* d_ws, size_t ws_size,
                              hipStream_t stream) {
    const float* raw   = (const float*)d_in[0];
    const float* W     = (const float*)d_in[1];
    const float* gamma = (const float*)d_in[2];
    const float* beta  = (const float*)d_in[3];
    const int*   idx   = (const int*)d_in[4];
    float* out = (float*)d_out;

    char* ws = (char*)d_ws;
    float* gstats = (float*)(ws + OFF_STATS);

    if (ws_size >= WS_NEEDED) {
        unsigned short* Wt   = (unsigned short*)(ws + OFF_WT);
        unsigned short* rawb = (unsigned short*)(ws + OFF_RAWB);
        unsigned short* xb   = (unsigned short*)(ws + OFF_XB);
        enc_conv<<<2048, 256, 0, stream>>>(raw, W, rawb, Wt, gstats);
        enc_gemm_b<<<1024, 256, 0, stream>>>(rawb, Wt, idx, xb, gstats);
        enc_bn_b<<<1024, 256, 0, stream>>>(xb, out, gstats, gamma, beta);
    } else {
        hipMemsetAsync(gstats, 0, 2 * FEAT * sizeof(float), stream);
        enc_gemm_f<<<1024, 256, 0, stream>>>(raw, W, idx, out, gstats);
        enc_bn_f<<<1024, 256, 0, stream>>>(out, gstats, gamma, beta);
    }
}